// Round 3
// baseline (1174.823 us; speedup 1.0000x reference)
//
#include <hip/hip_runtime.h>
#include <hip/hip_fp16.h>

// 2-layer GCN (PyG GCNConv), fp32 math. Round-21: SORT-FREE gather.
// k_sortb + colpk (per-node CSR lists) are deleted. Gathers are now
// edge-driven per coarse bucket: each block owns 256 dst nodes, holds
// acc[256][ch] fp32 in LDS, and streams the bucket's tin edges doing
// acc[dl][:] += (w * dinv[src]) * h[src] with LDS fp32 atomics. dinv is
// produced by a light per-bucket degree pass (k_deg). h and p are stored
// UNSCALED (dinv folded per-edge / in epilogues), which breaks the
// dinv->gemm1 dependency and removes the bf16 edge-weight quantization.
//
// h = x@W1 (fp16, unscaled)
// x2 = relu( dv_r*acc1 + dv_r^2*h[r] + b1 ),  acc1 = sum_e w*dinv[src]*h[src]
// p = x2@W2 (fp16, unscaled)   [fused in k_acc1]
// out[r] = dv_r*acc2 + dv_r^2*p[r] + b2,      acc2 = sum_e w*dinv[src]*p[src]

#define TPB 256
#define TPB_P 512
#define TPB_A 512
#define BSH2 8
#define BN2 256          // nodes per coarse bucket
#define NBC 512          // coarse bucket slots (391 used)
#define PCHUNK 4096
#define CAP2 5632        // slots/bucket: 4096 avg + 11sigma
#define CSTR 68          // acc1 LDS row stride (floats): mult of 4, %32==4
#define CSTR2 36         // acc2 LDS row stride

typedef union { uint2 u; __half2 h[2]; } hpack;
typedef union { uint4 u; __half2 h[4]; } hpack8;

// phase A: per-chunk LDS counting sort by coarse bucket, then linear copy-out.
// tin entry = (src | dl8<<17, ew fp32). bpos[b] = running count (memset 0).
__global__ __launch_bounds__(TPB_P) void k_part(const int* __restrict__ si,
                                                const int* __restrict__ di,
                                                const float* __restrict__ ew,
                                                int* __restrict__ bpos,
                                                int2* __restrict__ tin, int e) {
  __shared__ int hcnt[NBC];
  __shared__ int lst0[NBC];
  __shared__ int lcur[NBC];
  __shared__ int hbase[NBC];
  __shared__ int2 se[PCHUNK];
  __shared__ unsigned short sbk[PCHUNK];
  int t = threadIdx.x;
  int lo = blockIdx.x * PCHUNK;
  int hi = lo + PCHUNK; if (hi > e) hi = e;
  int cn = hi - lo;
  hcnt[t] = 0;  // TPB_P == NBC
  __syncthreads();
  for (int i = lo + t; i < hi; i += TPB_P) atomicAdd(&hcnt[di[i] >> BSH2], 1);
  __syncthreads();
  int c = hcnt[t];
  for (int off = 1; off < NBC; off <<= 1) {
    int u = (t >= off) ? hcnt[t - off] : 0;
    __syncthreads();
    hcnt[t] += u;
    __syncthreads();
  }
  {
    int ex = hcnt[t] - c;
    lst0[t] = ex;
    lcur[t] = 0;
    hbase[t] = c ? (t * CAP2 + atomicAdd(&bpos[t], c)) : 0;
  }
  __syncthreads();
  for (int i = lo + t; i < hi; i += TPB_P) {
    int d = di[i];
    int bk = d >> BSH2;
    int loc = atomicAdd(&lcur[bk], 1);
    int p = lst0[bk] + loc;
    se[p] = make_int2(si[i] | ((d & (BN2 - 1)) << 17), __float_as_int(ew[i]));
    sbk[p] = (unsigned short)bk;
  }
  __syncthreads();
  for (int p = t; p < cn; p += TPB_P) {  // sequential stores within runs
    int bk = sbk[p];
    tin[hbase[bk] + (p - lst0[bk])] = se[p];
  }
}

// per-bucket weighted degree -> dinv. degw init 1.0 = self-loop weight.
__global__ __launch_bounds__(TPB_A) void k_deg(const int2* __restrict__ tin,
                                               const int* __restrict__ bpos,
                                               float* __restrict__ dinv, int n) {
  __shared__ float degw[BN2];
  int b = blockIdx.x, t = threadIdx.x;
  if (t < BN2) degw[t] = 1.0f;
  __syncthreads();
  int jb = b * CAP2, je = jb + bpos[b];
  for (int j = jb + t; j < je; j += TPB_A) {
    int2 p = tin[j];
    atomicAdd(&degw[p.x >> 17], __int_as_float(p.y));
  }
  __syncthreads();
  int node = (b << BSH2) + t;
  if (t < BN2 && node < n) dinv[node] = rsqrtf(degw[t]);
}

// h = fp16(x @ W1), UNSCALED. 16 rows/block, 16 thr/row x 4 ch.
__global__ __launch_bounds__(TPB) void k_gemm1(const float* __restrict__ x,
                                               const float* __restrict__ W1,
                                               __half* __restrict__ h1h, int n) {
  __shared__ float Wl[64 * 64];
  int t = threadIdx.x;
  {
    const float4* W4 = (const float4*)W1;
    float4* Wl4 = (float4*)Wl;
#pragma unroll
    for (int i = 0; i < 4; ++i) Wl4[t + TPB * i] = W4[t + TPB * i];
  }
  __syncthreads();
  int r = blockIdx.x * 16 + (t >> 4);
  if (r >= n) return;
  int c0 = (t & 15) << 2;
  const float4* xr = (const float4*)(x + (size_t)r * 64);
  float ax = 0.f, ay = 0.f, az = 0.f, aw = 0.f;
#pragma unroll
  for (int kk = 0; kk < 16; ++kk) {
    float4 xv = xr[kk];
    const float* w = &Wl[(kk * 4) * 64 + c0];
    float4 w0 = *(const float4*)(w);
    float4 w1 = *(const float4*)(w + 64);
    float4 w2 = *(const float4*)(w + 128);
    float4 w3 = *(const float4*)(w + 192);
    ax += xv.x * w0.x + xv.y * w1.x + xv.z * w2.x + xv.w * w3.x;
    ay += xv.x * w0.y + xv.y * w1.y + xv.z * w2.y + xv.w * w3.y;
    az += xv.x * w0.z + xv.y * w1.z + xv.z * w2.z + xv.w * w3.z;
    aw += xv.x * w0.w + xv.y * w1.w + xv.z * w2.w + xv.w * w3.w;
  }
  hpack pk;
  pk.h[0] = __floats2half2_rn(ax, ay);
  pk.h[1] = __floats2half2_rn(az, aw);
  *(uint2*)(h1h + (size_t)r * 64 + c0) = pk.u;
}

// per-edge macro: one lane handles 8 channels (16B) of edge (pp), LDS-acc.
#define ACC_EDGE64(pp)                                                        \
  {                                                                           \
    int src = (pp).x & 0x1FFFF;                                               \
    float wd = __int_as_float((pp).y) * dinv[src];                            \
    hpack8 u; u.u = *(const uint4*)(h1h + (size_t)src * 64 + c0);             \
    float* A = &acc[((pp).x >> 17) * CSTR + c0];                              \
    _Pragma("unroll")                                                         \
    for (int k = 0; k < 4; ++k) {                                             \
      float2 f = __half22float2(u.h[k]);                                      \
      atomicAdd(A + 2 * k, wd * f.x);                                         \
      atomicAdd(A + 2 * k + 1, wd * f.y);                                     \
    }                                                                         \
  }

// FUSED: edge-driven layer-1 accumulate (LDS atomics) + relu epilogue +
// GEMM2 -> p (fp16, unscaled). One block per coarse bucket, 512 threads.
__global__ __launch_bounds__(TPB_A) void k_acc1(const __half* __restrict__ h1h,
                                                const int2* __restrict__ tin,
                                                const int* __restrict__ bpos,
                                                const float* __restrict__ dinv,
                                                const float* __restrict__ W2,
                                                const float* __restrict__ b1,
                                                __half* __restrict__ p2h, int n) {
  __shared__ float W2l[64 * 32];
  __shared__ float b1l[64];
  __shared__ float acc[BN2 * CSTR];
  int t = threadIdx.x, b = blockIdx.x;
  {
    const float4* W4 = (const float4*)W2;
    ((float4*)W2l)[t] = W4[t];  // 512 float4 = 2048 floats
    if (t < 64) b1l[t] = b1[t];
  }
  for (int i = t; i < BN2 * CSTR; i += TPB_A) acc[i] = 0.f;
  __syncthreads();
  int jb = b * CAP2, je = jb + bpos[b];
  int c0 = (t & 7) << 3;           // 8 lanes/edge x 8 ch
  int j = jb + (t >> 3);           // 64 edges in flight per pass
  for (; j + 192 < je; j += 256) { // unroll 4 for MLP
    int2 pa = tin[j], pb = tin[j + 64], pc = tin[j + 128], pd = tin[j + 192];
    ACC_EDGE64(pa); ACC_EDGE64(pb); ACC_EDGE64(pc); ACC_EDGE64(pd);
  }
  for (; j < je; j += 64) { int2 pa = tin[j]; ACC_EDGE64(pa); }
  __syncthreads();
  // x2 = relu(dv*acc + dv^2*h_self + b1), in-place in acc (fp32).
#pragma unroll
  for (int pass = 0; pass < 4; ++pass) {
    int ndl = pass * 64 + (t >> 3);
    int node = (b << BSH2) + ndl;
    if (node < n) {
      float dv = dinv[node];
      float dv2 = dv * dv;
      hpack8 s; s.u = *(const uint4*)(h1h + (size_t)node * 64 + c0);
      float* A = &acc[ndl * CSTR + c0];
#pragma unroll
      for (int k = 0; k < 4; ++k) {
        float2 f = __half22float2(s.h[k]);
        A[2 * k]     = fmaxf(dv * A[2 * k]     + dv2 * f.x + b1l[c0 + 2 * k], 0.f);
        A[2 * k + 1] = fmaxf(dv * A[2 * k + 1] + dv2 * f.y + b1l[c0 + 2 * k + 1], 0.f);
      }
    }
  }
  __syncthreads();
  // GEMM2: p[nd][oc] = sum_k x2[nd][k] * W2[k][oc]; 2048 items, 4/thread.
#pragma unroll
  for (int it = 0; it < 4; ++it) {
    int item = t + (it << 9);
    int ndl = item >> 3;
    int oc = (item & 7) << 2;
    int node = (b << BSH2) + ndl;
    if (node >= n) continue;
    const float* xr = &acc[ndl * CSTR];
    float ax = 0.f, ay = 0.f, az = 0.f, aw = 0.f;
#pragma unroll
    for (int kk = 0; kk < 16; ++kk) {
      float4 xv = *(const float4*)(xr + 4 * kk);
      const float* w = &W2l[(kk * 4) * 32 + oc];
      float4 w0 = *(const float4*)(w);
      float4 w1 = *(const float4*)(w + 32);
      float4 w2 = *(const float4*)(w + 64);
      float4 w3 = *(const float4*)(w + 96);
      ax += xv.x * w0.x + xv.y * w1.x + xv.z * w2.x + xv.w * w3.x;
      ay += xv.x * w0.y + xv.y * w1.y + xv.z * w2.y + xv.w * w3.y;
      az += xv.x * w0.z + xv.y * w1.z + xv.z * w2.z + xv.w * w3.z;
      aw += xv.x * w0.w + xv.y * w1.w + xv.z * w2.w + xv.w * w3.w;
    }
    hpack pk;
    pk.h[0] = __floats2half2_rn(ax, ay);
    pk.h[1] = __floats2half2_rn(az, aw);
    *(uint2*)(p2h + (size_t)node * 32 + oc) = pk.u;
  }
}

#define ACC_EDGE32(pp)                                                        \
  {                                                                           \
    int src = (pp).x & 0x1FFFF;                                               \
    float wd = __int_as_float((pp).y) * dinv[src];                            \
    hpack8 u; u.u = *(const uint4*)(p2h + (size_t)src * 32 + c0);             \
    float* A = &acc[((pp).x >> 17) * CSTR2 + c0];                             \
    _Pragma("unroll")                                                         \
    for (int k = 0; k < 4; ++k) {                                             \
      float2 f = __half22float2(u.h[k]);                                      \
      atomicAdd(A + 2 * k, wd * f.x);                                         \
      atomicAdd(A + 2 * k + 1, wd * f.y);                                     \
    }                                                                         \
  }

// edge-driven layer-2 accumulate + epilogue: out = dv*acc + dv^2*p_self + b2.
__global__ __launch_bounds__(TPB_A) void k_acc2(const __half* __restrict__ p2h,
                                                const int2* __restrict__ tin,
                                                const int* __restrict__ bpos,
                                                const float* __restrict__ dinv,
                                                const float* __restrict__ b2,
                                                float* __restrict__ out, int n) {
  __shared__ float acc[BN2 * CSTR2];
  int t = threadIdx.x, b = blockIdx.x;
  for (int i = t; i < BN2 * CSTR2; i += TPB_A) acc[i] = 0.f;
  __syncthreads();
  int jb = b * CAP2, je = jb + bpos[b];
  int c0 = (t & 3) << 3;            // 4 lanes/edge x 8 ch
  int j = jb + (t >> 2);            // 128 edges in flight per pass
  for (; j + 384 < je; j += 512) {  // unroll 4
    int2 pa = tin[j], pb = tin[j + 128], pc = tin[j + 256], pd = tin[j + 384];
    ACC_EDGE32(pa); ACC_EDGE32(pb); ACC_EDGE32(pc); ACC_EDGE32(pd);
  }
  for (; j < je; j += 128) { int2 pa = tin[j]; ACC_EDGE32(pa); }
  __syncthreads();
#pragma unroll
  for (int pass = 0; pass < 2; ++pass) {
    int ndl = pass * 128 + (t >> 2);
    int node = (b << BSH2) + ndl;
    if (node < n) {
      float dv = dinv[node];
      float dv2 = dv * dv;
      hpack8 s; s.u = *(const uint4*)(p2h + (size_t)node * 32 + c0);
      const float* A = &acc[ndl * CSTR2 + c0];
      const float4* b24 = (const float4*)(b2 + c0);
      float4 bb0 = b24[0], bb1 = b24[1];
      float2 f0 = __half22float2(s.h[0]), f1 = __half22float2(s.h[1]);
      float2 f2 = __half22float2(s.h[2]), f3 = __half22float2(s.h[3]);
      float* op = out + (size_t)node * 32 + c0;
      *(float4*)(op) = make_float4(dv * A[0] + dv2 * f0.x + bb0.x,
                                   dv * A[1] + dv2 * f0.y + bb0.y,
                                   dv * A[2] + dv2 * f1.x + bb0.z,
                                   dv * A[3] + dv2 * f1.y + bb0.w);
      *(float4*)(op + 4) = make_float4(dv * A[4] + dv2 * f2.x + bb1.x,
                                       dv * A[5] + dv2 * f2.y + bb1.y,
                                       dv * A[6] + dv2 * f3.x + bb1.z,
                                       dv * A[7] + dv2 * f3.y + bb1.w);
    }
  }
}

extern "C" void kernel_launch(void* const* d_in, const int* in_sizes, int n_in,
                              void* d_out, int out_size, void* d_ws, size_t ws_size,
                              hipStream_t stream) {
  const float* x  = (const float*)d_in[0];
  const int* ei   = (const int*)d_in[1];
  const float* ew = (const float*)d_in[2];
  const float* W1 = (const float*)d_in[3];
  const float* b1 = (const float*)d_in[4];
  const float* W2 = (const float*)d_in[5];
  const float* b2 = (const float*)d_in[6];
  float* out = (float*)d_out;

  const int n = in_sizes[0] / 64;  // 100000
  const int e = in_sizes[1] / 2;   // 1600000
  const int* si = ei;
  const int* di = ei + e;
  const int NBc = (n + BN2 - 1) >> BSH2;  // 391 coarse buckets

  // workspace layout (float-sized units), ~37 MB.
  float* ws = (float*)d_ws;
  const size_t NP = 100352;
  const size_t SLOTS = (size_t)NBc * CAP2;            // 2.20M
  float*  dinv   = ws;                                // [NP]
  __half* h1h    = (__half*)(ws + NP);                // [n*64 halves] unscaled h
  int*    bpos   = (int*)(ws + NP + (size_t)n * 32);  // [NBC] (memset 0)
  int2*   tin    = (int2*)(bpos + 1024);              // [SLOTS] int2
  __half* p2h    = (__half*)(tin + SLOTS);            // [n*32 halves] unscaled p

  int gb_part = (e + PCHUNK - 1) / PCHUNK;  // 391
  int gb_g1 = (n + 15) / 16;

  hipMemsetAsync(bpos, 0, NBC * sizeof(int), stream);
  k_part<<<gb_part, TPB_P, 0, stream>>>(si, di, ew, bpos, tin, e);
  k_deg<<<NBc, TPB_A, 0, stream>>>(tin, bpos, dinv, n);
  k_gemm1<<<gb_g1, TPB, 0, stream>>>(x, W1, h1h, n);
  k_acc1<<<NBc, TPB_A, 0, stream>>>(h1h, tin, bpos, dinv, W2, b1, p2h, n);
  k_acc2<<<NBc, TPB_A, 0, stream>>>(p2h, tin, bpos, dinv, b2, out, n);
}

// Round 4
// 202.998 us; speedup vs baseline: 5.7874x; 5.7874x over previous
//
#include <hip/hip_runtime.h>
#include <hip/hip_fp16.h>

// 2-layer GCN (PyG GCNConv), fp32 math — per-node CSR gather, fp16 payloads,
// 4-byte colpk edge entries. Round-22: restore the proven r20 pipeline
// (r21's edge-driven LDS-atomic accumulate was 17-100x slower: 102M
// ds_add_f32 serialize; register-private accumulate via sorted lists is the
// right structure). New: k_gemm1 is fused into k_part's dispatch as a FAT
// kernel (blocks 0..390 = part, rest = gemm1), possible because h is now
// stored UNSCALED; gathers fold dinv[src] per edge (r21-validated numerics,
// absmax identical). Saves the serial ~9us gemm1 slot.
//
// h = x@W1 (fp16, unscaled)                                  [fat, || part]
// acc1 = dv_r*h[r] + sum_e (w_e*dinv[src])*h[src]            (fp32 regs)
// x2 = relu(dv_r*acc1 + b1); p = x2@W2 (fp16, unscaled)      [fused k_gfuse]
// out[r] = dv_r*( dv_r*p[r] + sum_j (w_j*dinv[src])*p[src] ) + b2

#define TPB 256
#define TPB_P 512
#define TPB_S 1024
#define BSH2 8
#define BN2 256          // nodes per coarse bucket
#define NBC 512          // coarse bucket slots (391 used)
#define PCHUNK 4096
#define CAP2 5632        // slots/bucket: 4096 avg + 11sigma + <=3/node pads
#define XSTR 68          // x2 LDS row stride (floats)

typedef union { uint2 u; __half2 h[2]; } hpack;
typedef union { uint4 u; __half2 h[4]; } hpack8;

__device__ __forceinline__ int enc_w(float w) {  // bf16 RNE, sign dropped
  unsigned b = __float_as_uint(w);
  return (int)(((b + 0x7FFFu + ((b >> 16) & 1u)) >> 16) & 0x7FFFu);
}
__device__ __forceinline__ float dec_w(int e) {
  return __uint_as_float(((unsigned)e >> 17) << 16);
}

// FAT kernel: blocks [0, gbp) run phase-A partition (per-chunk LDS counting
// sort by coarse bucket -> tin, bucket-major); blocks [gbp, ...) run
// h = fp16(x @ W1) UNSCALED (32 rows/block, 16 thr/row x 4 ch).
// Independent work co-scheduled: gemm1 hides under part's latency phase.
__global__ __launch_bounds__(TPB_P) void k_fat(const int* __restrict__ si,
                                               const int* __restrict__ di,
                                               const float* __restrict__ ew,
                                               int* __restrict__ bpos,
                                               int2* __restrict__ tin,
                                               const float* __restrict__ x,
                                               const float* __restrict__ W1,
                                               __half* __restrict__ h1h,
                                               int e, int n, int gbp) {
  __shared__ union SM {
    struct {
      int hcnt[NBC]; int lst0[NBC]; int lcur[NBC]; int hbase[NBC];
      int2 se[PCHUNK]; unsigned short sbk[PCHUNK];
    } p;                    // 48 KB
    float Wl[64 * 64];      // 16 KB
  } sm;
  int t = threadIdx.x;
  if (blockIdx.x < (unsigned)gbp) {
    // ---------------- phase A: partition (proven r18/r20 body) ------------
    int lo = blockIdx.x * PCHUNK;
    int hi = lo + PCHUNK; if (hi > e) hi = e;
    int cn = hi - lo;
    sm.p.hcnt[t] = 0;  // TPB_P == NBC
    __syncthreads();
    for (int i = lo + t; i < hi; i += TPB_P) atomicAdd(&sm.p.hcnt[di[i] >> BSH2], 1);
    __syncthreads();
    int c = sm.p.hcnt[t];
    for (int off = 1; off < NBC; off <<= 1) {
      int u = (t >= off) ? sm.p.hcnt[t - off] : 0;
      __syncthreads();
      sm.p.hcnt[t] += u;
      __syncthreads();
    }
    {
      int ex = sm.p.hcnt[t] - c;
      sm.p.lst0[t] = ex;
      sm.p.lcur[t] = 0;
      sm.p.hbase[t] = c ? (t * CAP2 + atomicAdd(&bpos[t], c)) : 0;
    }
    __syncthreads();
    for (int i = lo + t; i < hi; i += TPB_P) {
      int d = di[i];
      int bk = d >> BSH2;
      int loc = atomicAdd(&sm.p.lcur[bk], 1);
      int p = sm.p.lst0[bk] + loc;
      sm.p.se[p] = make_int2(si[i] | ((d & (BN2 - 1)) << 17), __float_as_int(ew[i]));
      sm.p.sbk[p] = (unsigned short)bk;
    }
    __syncthreads();
    for (int p = t; p < cn; p += TPB_P) {  // sequential stores within runs
      int bk = sm.p.sbk[p];
      tin[sm.p.hbase[bk] + (p - sm.p.lst0[bk])] = sm.p.se[p];
    }
  } else {
    // ---------------- gemm1: h = fp16(x @ W1), unscaled -------------------
    {
      const float4* W4 = (const float4*)W1;
      float4* Wl4 = (float4*)sm.Wl;
#pragma unroll
      for (int i = 0; i < 2; ++i) Wl4[t + TPB_P * i] = W4[t + TPB_P * i];
    }
    __syncthreads();
    int r = (blockIdx.x - gbp) * 32 + (t >> 4);
    if (r >= n) return;
    int c0 = (t & 15) << 2;
    const float4* xr = (const float4*)(x + (size_t)r * 64);
    float ax = 0.f, ay = 0.f, az = 0.f, aw = 0.f;
#pragma unroll
    for (int kk = 0; kk < 16; ++kk) {
      float4 xv = xr[kk];
      const float* w = &sm.Wl[(kk * 4) * 64 + c0];
      float4 w0 = *(const float4*)(w);
      float4 w1 = *(const float4*)(w + 64);
      float4 w2 = *(const float4*)(w + 128);
      float4 w3 = *(const float4*)(w + 192);
      ax += xv.x * w0.x + xv.y * w1.x + xv.z * w2.x + xv.w * w3.x;
      ay += xv.x * w0.y + xv.y * w1.y + xv.z * w2.y + xv.w * w3.y;
      az += xv.x * w0.z + xv.y * w1.z + xv.z * w2.z + xv.w * w3.z;
      aw += xv.x * w0.w + xv.y * w1.w + xv.z * w2.w + xv.w * w3.w;
    }
    hpack pk;
    pk.h[0] = __floats2half2_rn(ax, ay);
    pk.h[1] = __floats2half2_rn(az, aw);
    *(uint2*)(h1h + (size_t)r * 64 + c0) = pk.u;
  }
}

// phase B: per-coarse-bucket (256 nodes) counting sort -> per-node 4B edge
// lists (x4-padded, 16B-aligned starts) + rowseg + dinv. 391 blocks x 1024.
__global__ __launch_bounds__(TPB_S) void k_sortb(const int2* __restrict__ tin,
                                                 const int* __restrict__ bpos,
                                                 int* __restrict__ colpk,
                                                 int2* __restrict__ rowseg,
                                                 float* __restrict__ dinv, int n) {
  __shared__ int cnt[BN2];
  __shared__ float degw[BN2];
  __shared__ int cur[BN2];
  __shared__ int ls[BN2];
  __shared__ int2 se[PCHUNK];
  int b = blockIdx.x, t = threadIdx.x;
  if (t < BN2) { cnt[t] = 0; degw[t] = 1.0f; }  // self-loop weight
  __syncthreads();
  int jb = b * CAP2, je = jb + bpos[b];
  for (int j = jb + t; j < je; j += TPB_S) {
    int2 p = tin[j];
    int o = j - jb;
    if (o < PCHUNK) se[o] = p;  // LDS cache for the scatter pass
    int dl = p.x >> 17;
    atomicAdd(&cnt[dl], 1);
    atomicAdd(&degw[dl], __int_as_float(p.y));  // fp32 degree
  }
  __syncthreads();
  int c = (t < BN2) ? cnt[t] : 0;
  int c4 = (c + 3) & ~3;  // pad to multiple of 4 entries (16B)
  if (t < BN2) ls[t] = c4;
  __syncthreads();
  for (int off = 1; off < BN2; off <<= 1) {
    int u = (t >= off && t < BN2) ? ls[t - off] : 0;
    __syncthreads();
    if (t < BN2) ls[t] += u;
    __syncthreads();
  }
  int base = b << BSH2;
  if (t < BN2) {
    int start = jb + ls[t] - c4;  // 4-aligned offset -> 16B-aligned
    cur[t] = start;
    int node = base + t;
    if (node < n) {
      rowseg[node] = make_int2(start, start + c4);
      dinv[node] = rsqrtf(degw[t]);
    }
    for (int i = c; i < c4; ++i) colpk[start + i] = 0;  // zero-weight pads
  }
  __syncthreads();
  for (int j = jb + t; j < je; j += TPB_S) {
    int o = j - jb;
    int2 p = (o < PCHUNK) ? se[o] : tin[j];
    int dl = p.x >> 17;
    int pos = atomicAdd(&cur[dl], 1);
    colpk[pos] = (p.x & 0x1FFFF) | (enc_w(__int_as_float(p.y)) << 17);
  }
}

// FUSED gather64 + gemm2. 32 nodes/block, 8 thr/node x 8 ch gather ->
// x2 = relu(dinv*acc + b1) -> LDS tile -> p = fp16(x2 @ W2), unscaled.
// h is unscaled; wd = w*dinv[src] folded per edge (self: wd = dinv[r]).
__global__ __launch_bounds__(TPB) void k_gfuse(const __half* __restrict__ g1h,
                                               const int* __restrict__ colpk,
                                               const int2* __restrict__ rowseg,
                                               const float* __restrict__ dinv,
                                               const float* __restrict__ W2,
                                               const float* __restrict__ b1,
                                               __half* __restrict__ g2h, int n) {
  __shared__ float W2l[64 * 32];
  __shared__ float b1l[64];
  __shared__ float x2l[32 * XSTR];
  int t = threadIdx.x;
  {
    const float4* W4 = (const float4*)W2;
    float4* Wl4 = (float4*)W2l;
#pragma unroll
    for (int i = 0; i < 2; ++i) Wl4[t + TPB * i] = W4[t + TPB * i];
    if (t < 64) b1l[t] = b1[t];
  }
  __syncthreads();  // RACE FIX: b1l is read pre-GEMM-barrier in the epilogue
  int node = t >> 3;
  int r = blockIdx.x * 32 + node;
  int c0 = (t & 7) << 3;
  bool valid = (r < n);
  float a[8];
  float dv = 0.f;
  if (valid) {
    dv = dinv[r];
    hpack8 s; s.u = *(const uint4*)(g1h + (size_t)r * 64 + c0);  // self-loop
#pragma unroll
    for (int k = 0; k < 4; ++k) {
      float2 f = __half22float2(s.h[k]);
      a[2 * k] = dv * f.x; a[2 * k + 1] = dv * f.y;  // self wd = dinv[r]
    }
    int2 seg = rowseg[r];
    int j = seg.x;
    for (; j + 7 < seg.y; j += 8) {
      int4 qa = *(const int4*)(colpk + j);
      int4 qb = *(const int4*)(colpk + j + 4);
      int s0 = qa.x & 0x1FFFF, s1 = qa.y & 0x1FFFF, s2 = qa.z & 0x1FFFF, s3 = qa.w & 0x1FFFF;
      int s4 = qb.x & 0x1FFFF, s5 = qb.y & 0x1FFFF, s6 = qb.z & 0x1FFFF, s7 = qb.w & 0x1FFFF;
      hpack8 u0; u0.u = *(const uint4*)(g1h + (size_t)s0 * 64 + c0);
      hpack8 u1; u1.u = *(const uint4*)(g1h + (size_t)s1 * 64 + c0);
      hpack8 u2; u2.u = *(const uint4*)(g1h + (size_t)s2 * 64 + c0);
      hpack8 u3; u3.u = *(const uint4*)(g1h + (size_t)s3 * 64 + c0);
      hpack8 u4; u4.u = *(const uint4*)(g1h + (size_t)s4 * 64 + c0);
      hpack8 u5; u5.u = *(const uint4*)(g1h + (size_t)s5 * 64 + c0);
      hpack8 u6; u6.u = *(const uint4*)(g1h + (size_t)s6 * 64 + c0);
      hpack8 u7; u7.u = *(const uint4*)(g1h + (size_t)s7 * 64 + c0);
      float w0 = dec_w(qa.x) * dinv[s0], w1 = dec_w(qa.y) * dinv[s1];
      float w2 = dec_w(qa.z) * dinv[s2], w3 = dec_w(qa.w) * dinv[s3];
      float w4 = dec_w(qb.x) * dinv[s4], w5 = dec_w(qb.y) * dinv[s5];
      float w6 = dec_w(qb.z) * dinv[s6], w7 = dec_w(qb.w) * dinv[s7];
#pragma unroll
      for (int k = 0; k < 4; ++k) {
        float2 f;
        f = __half22float2(u0.h[k]); a[2*k] += w0 * f.x; a[2*k+1] += w0 * f.y;
        f = __half22float2(u1.h[k]); a[2*k] += w1 * f.x; a[2*k+1] += w1 * f.y;
        f = __half22float2(u2.h[k]); a[2*k] += w2 * f.x; a[2*k+1] += w2 * f.y;
        f = __half22float2(u3.h[k]); a[2*k] += w3 * f.x; a[2*k+1] += w3 * f.y;
        f = __half22float2(u4.h[k]); a[2*k] += w4 * f.x; a[2*k+1] += w4 * f.y;
        f = __half22float2(u5.h[k]); a[2*k] += w5 * f.x; a[2*k+1] += w5 * f.y;
        f = __half22float2(u6.h[k]); a[2*k] += w6 * f.x; a[2*k+1] += w6 * f.y;
        f = __half22float2(u7.h[k]); a[2*k] += w7 * f.x; a[2*k+1] += w7 * f.y;
      }
    }
    if (j < seg.y) {  // exactly 4 remain (x4-padded)
      int4 qa = *(const int4*)(colpk + j);
      int s0 = qa.x & 0x1FFFF, s1 = qa.y & 0x1FFFF, s2 = qa.z & 0x1FFFF, s3 = qa.w & 0x1FFFF;
      hpack8 u0; u0.u = *(const uint4*)(g1h + (size_t)s0 * 64 + c0);
      hpack8 u1; u1.u = *(const uint4*)(g1h + (size_t)s1 * 64 + c0);
      hpack8 u2; u2.u = *(const uint4*)(g1h + (size_t)s2 * 64 + c0);
      hpack8 u3; u3.u = *(const uint4*)(g1h + (size_t)s3 * 64 + c0);
      float w0 = dec_w(qa.x) * dinv[s0], w1 = dec_w(qa.y) * dinv[s1];
      float w2 = dec_w(qa.z) * dinv[s2], w3 = dec_w(qa.w) * dinv[s3];
#pragma unroll
      for (int k = 0; k < 4; ++k) {
        float2 f;
        f = __half22float2(u0.h[k]); a[2*k] += w0 * f.x; a[2*k+1] += w0 * f.y;
        f = __half22float2(u1.h[k]); a[2*k] += w1 * f.x; a[2*k+1] += w1 * f.y;
        f = __half22float2(u2.h[k]); a[2*k] += w2 * f.x; a[2*k+1] += w2 * f.y;
        f = __half22float2(u3.h[k]); a[2*k] += w3 * f.x; a[2*k+1] += w3 * f.y;
      }
    }
    float* xp = x2l + node * XSTR + c0;
#pragma unroll
    for (int k = 0; k < 8; k += 4) {
      float4 v = {fmaxf(dv * a[k + 0] + b1l[c0 + k + 0], 0.f),
                  fmaxf(dv * a[k + 1] + b1l[c0 + k + 1], 0.f),
                  fmaxf(dv * a[k + 2] + b1l[c0 + k + 2], 0.f),
                  fmaxf(dv * a[k + 3] + b1l[c0 + k + 3], 0.f)};
      *(float4*)(xp + k) = v;
    }
  }
  __syncthreads();
  if (!valid) return;
  int oc = (t & 7) << 2;
  const float* xr = x2l + node * XSTR;
  float ax = 0.f, ay = 0.f, az = 0.f, aw = 0.f;
#pragma unroll
  for (int kk = 0; kk < 16; ++kk) {
    float4 xv = *(const float4*)(xr + 4 * kk);
    const float* w = &W2l[(kk * 4) * 32 + oc];
    float4 w0 = *(const float4*)(w);
    float4 w1 = *(const float4*)(w + 32);
    float4 w2 = *(const float4*)(w + 64);
    float4 w3 = *(const float4*)(w + 96);
    ax += xv.x * w0.x + xv.y * w1.x + xv.z * w2.x + xv.w * w3.x;
    ay += xv.x * w0.y + xv.y * w1.y + xv.z * w2.y + xv.w * w3.y;
    az += xv.x * w0.z + xv.y * w1.z + xv.z * w2.z + xv.w * w3.z;
    aw += xv.x * w0.w + xv.y * w1.w + xv.z * w2.w + xv.w * w3.w;
  }
  hpack pk;
  pk.h[0] = __floats2half2_rn(ax, ay);   // p stored UNSCALED
  pk.h[1] = __floats2half2_rn(az, aw);
  *(uint2*)(g2h + (size_t)r * 32 + oc) = pk.u;
}

// out[r] = dv*( dv*p[r] + sum_j (w_j*dinv[src])*p[src] ) + b2. 4 thr/node.
__global__ __launch_bounds__(TPB) void k_gather32(const __half* __restrict__ g2h,
                                                  const int* __restrict__ colpk,
                                                  const int2* __restrict__ rowseg,
                                                  const float* __restrict__ dinv,
                                                  const float* __restrict__ b2,
                                                  float* __restrict__ out, int n) {
  int t = threadIdx.x;
  int r = blockIdx.x * 64 + (t >> 2);
  if (r >= n) return;
  int c0 = (t & 3) << 3;
  float dv = dinv[r];
  float a[8];
  {
    hpack8 s; s.u = *(const uint4*)(g2h + (size_t)r * 32 + c0);  // self-loop
#pragma unroll
    for (int k = 0; k < 4; ++k) {
      float2 f = __half22float2(s.h[k]);
      a[2 * k] = dv * f.x; a[2 * k + 1] = dv * f.y;  // self wd = dinv[r]
    }
  }
  int2 seg = rowseg[r];
  int j = seg.x;
  for (; j + 7 < seg.y; j += 8) {
    int4 qa = *(const int4*)(colpk + j);
    int4 qb = *(const int4*)(colpk + j + 4);
    int s0 = qa.x & 0x1FFFF, s1 = qa.y & 0x1FFFF, s2 = qa.z & 0x1FFFF, s3 = qa.w & 0x1FFFF;
    int s4 = qb.x & 0x1FFFF, s5 = qb.y & 0x1FFFF, s6 = qb.z & 0x1FFFF, s7 = qb.w & 0x1FFFF;
    hpack8 u0; u0.u = *(const uint4*)(g2h + (size_t)s0 * 32 + c0);
    hpack8 u1; u1.u = *(const uint4*)(g2h + (size_t)s1 * 32 + c0);
    hpack8 u2; u2.u = *(const uint4*)(g2h + (size_t)s2 * 32 + c0);
    hpack8 u3; u3.u = *(const uint4*)(g2h + (size_t)s3 * 32 + c0);
    hpack8 u4; u4.u = *(const uint4*)(g2h + (size_t)s4 * 32 + c0);
    hpack8 u5; u5.u = *(const uint4*)(g2h + (size_t)s5 * 32 + c0);
    hpack8 u6; u6.u = *(const uint4*)(g2h + (size_t)s6 * 32 + c0);
    hpack8 u7; u7.u = *(const uint4*)(g2h + (size_t)s7 * 32 + c0);
    float w0 = dec_w(qa.x) * dinv[s0], w1 = dec_w(qa.y) * dinv[s1];
    float w2 = dec_w(qa.z) * dinv[s2], w3 = dec_w(qa.w) * dinv[s3];
    float w4 = dec_w(qb.x) * dinv[s4], w5 = dec_w(qb.y) * dinv[s5];
    float w6 = dec_w(qb.z) * dinv[s6], w7 = dec_w(qb.w) * dinv[s7];
#pragma unroll
    for (int k = 0; k < 4; ++k) {
      float2 f;
      f = __half22float2(u0.h[k]); a[2*k] += w0 * f.x; a[2*k+1] += w0 * f.y;
      f = __half22float2(u1.h[k]); a[2*k] += w1 * f.x; a[2*k+1] += w1 * f.y;
      f = __half22float2(u2.h[k]); a[2*k] += w2 * f.x; a[2*k+1] += w2 * f.y;
      f = __half22float2(u3.h[k]); a[2*k] += w3 * f.x; a[2*k+1] += w3 * f.y;
      f = __half22float2(u4.h[k]); a[2*k] += w4 * f.x; a[2*k+1] += w4 * f.y;
      f = __half22float2(u5.h[k]); a[2*k] += w5 * f.x; a[2*k+1] += w5 * f.y;
      f = __half22float2(u6.h[k]); a[2*k] += w6 * f.x; a[2*k+1] += w6 * f.y;
      f = __half22float2(u7.h[k]); a[2*k] += w7 * f.x; a[2*k+1] += w7 * f.y;
    }
  }
  if (j < seg.y) {  // exactly 4 remain
    int4 qa = *(const int4*)(colpk + j);
    int s0 = qa.x & 0x1FFFF, s1 = qa.y & 0x1FFFF, s2 = qa.z & 0x1FFFF, s3 = qa.w & 0x1FFFF;
    hpack8 u0; u0.u = *(const uint4*)(g2h + (size_t)s0 * 32 + c0);
    hpack8 u1; u1.u = *(const uint4*)(g2h + (size_t)s1 * 32 + c0);
    hpack8 u2; u2.u = *(const uint4*)(g2h + (size_t)s2 * 32 + c0);
    hpack8 u3; u3.u = *(const uint4*)(g2h + (size_t)s3 * 32 + c0);
    float w0 = dec_w(qa.x) * dinv[s0], w1 = dec_w(qa.y) * dinv[s1];
    float w2 = dec_w(qa.z) * dinv[s2], w3 = dec_w(qa.w) * dinv[s3];
#pragma unroll
    for (int k = 0; k < 4; ++k) {
      float2 f;
      f = __half22float2(u0.h[k]); a[2*k] += w0 * f.x; a[2*k+1] += w0 * f.y;
      f = __half22float2(u1.h[k]); a[2*k] += w1 * f.x; a[2*k+1] += w1 * f.y;
      f = __half22float2(u2.h[k]); a[2*k] += w2 * f.x; a[2*k+1] += w2 * f.y;
      f = __half22float2(u3.h[k]); a[2*k] += w3 * f.x; a[2*k+1] += w3 * f.y;
    }
  }
  const float4* b24 = (const float4*)(b2 + c0);
  float4 bb0 = b24[0], bb1 = b24[1];
  float* op = out + (size_t)r * 32 + c0;
  *(float4*)(op)     = make_float4(dv * a[0] + bb0.x, dv * a[1] + bb0.y,
                                   dv * a[2] + bb0.z, dv * a[3] + bb0.w);
  *(float4*)(op + 4) = make_float4(dv * a[4] + bb1.x, dv * a[5] + bb1.y,
                                   dv * a[6] + bb1.z, dv * a[7] + bb1.w);
}

extern "C" void kernel_launch(void* const* d_in, const int* in_sizes, int n_in,
                              void* d_out, int out_size, void* d_ws, size_t ws_size,
                              hipStream_t stream) {
  const float* x  = (const float*)d_in[0];
  const int* ei   = (const int*)d_in[1];
  const float* ew = (const float*)d_in[2];
  const float* W1 = (const float*)d_in[3];
  const float* b1 = (const float*)d_in[4];
  const float* W2 = (const float*)d_in[5];
  const float* b2 = (const float*)d_in[6];
  float* out = (float*)d_out;

  const int n = in_sizes[0] / 64;  // 100000
  const int e = in_sizes[1] / 2;   // 1600000
  const int* si = ei;
  const int* di = ei + e;
  const int NBc = (n + BN2 - 1) >> BSH2;  // 391 coarse buckets

  // workspace layout (float-sized units), ~55 MB.
  float* ws = (float*)d_ws;
  const size_t NP = 100352;
  const size_t SLOTS = (size_t)NBc * CAP2;            // 2.20M
  float*  dinv   = ws;                                // [NP]
  __half* g1h    = (__half*)(ws + NP);                // [n*64 halves] unscaled h
  int2*   rowseg = (int2*)(ws + NP + (size_t)n * 32); // [NP]
  int*    bpos   = (int*)(rowseg + NP);               // [NBC] counts (memset 0)
  int*    colpk  = bpos + 1024;                       // [SLOTS] 4B entries
  int2*   tin    = (int2*)(colpk + SLOTS);            // [SLOTS] int2
  __half* g2h    = (__half*)(tin + SLOTS);            // [n*32 halves] unscaled p

  int gb_part = (e + PCHUNK - 1) / PCHUNK;  // 391
  int gb_g1 = (n + 31) / 32;                // 3125 (32 rows/block @ 512 thr)
  int gb_gf = (n + 31) / 32;
  int gb_g32 = (n + 63) / 64;

  hipMemsetAsync(bpos, 0, NBC * sizeof(int), stream);
  k_fat<<<gb_part + gb_g1, TPB_P, 0, stream>>>(si, di, ew, bpos, tin,
                                               x, W1, g1h, e, n, gb_part);
  k_sortb<<<NBc, TPB_S, 0, stream>>>(tin, bpos, colpk, rowseg, dinv, n);
  k_gfuse<<<gb_gf, TPB, 0, stream>>>(g1h, colpk, rowseg, dinv, W2, b1, g2h, n);
  k_gather32<<<gb_g32, TPB, 0, stream>>>(g2h, colpk, rowseg, dinv, b2, out, n);
}